// Round 1
// baseline (2081.989 us; speedup 1.0000x reference)
//
#include <hip/hip_runtime.h>
#include <math.h>

#define N_NODES 100000
#define D 128
#define E_EDGES 600000
#define BN_EPS 1e-5f
#define BM 64

// ---------------- degree histogram ----------------
__global__ __launch_bounds__(256) void hist_kernel(
    const int* __restrict__ src, const int* __restrict__ dst,
    int* __restrict__ outdeg, int* __restrict__ indeg)
{
    int i = blockIdx.x * 256 + threadIdx.x;
    if (i < E_EDGES) {
        atomicAdd(&outdeg[src[i]], 1);
        atomicAdd(&indeg[dst[i]], 1);
    }
}

// ---------------- norms ----------------
__global__ __launch_bounds__(256) void norm_kernel(
    const int* __restrict__ outdeg, const int* __restrict__ indeg,
    float* __restrict__ ns, float* __restrict__ nd)
{
    int n = blockIdx.x * 256 + threadIdx.x;
    int r = blockIdx.y;
    if (n < N_NODES) {
        int od = outdeg[r * N_NODES + n];
        int id = indeg[r * N_NODES + n];
        ns[r * N_NODES + n] = rsqrtf((float)(od < 1 ? 1 : od));
        nd[r * N_NODES + n] = rsqrtf((float)(id < 1 ? 1 : id));
    }
}

// ---------------- exclusive scan of in-degrees -> CSR row_ptr (+cursor copy) ----------------
// one block per relation, 1024 threads, int4 chunks (N divisible by 4)
__global__ __launch_bounds__(1024) void scan_kernel(
    const int* __restrict__ indeg, int* __restrict__ rowptr, int* __restrict__ cursor)
{
    const int r = blockIdx.x;
    const int4* deg4 = (const int4*)(indeg + (size_t)r * N_NODES);
    int* rp = rowptr + (size_t)r * (N_NODES + 1);
    int* cur = cursor + (size_t)r * N_NODES;

    __shared__ int wsum[16];
    __shared__ int woff[16];
    __shared__ int chunk_total;

    const int tid = threadIdx.x;
    const int lane = tid & 63;
    const int wid = tid >> 6;
    const int N4 = N_NODES / 4;   // 25000

    int running = 0;
    for (int base4 = 0; base4 < N4; base4 += 1024) {
        int i4 = base4 + tid;
        int4 v = (i4 < N4) ? deg4[i4] : make_int4(0, 0, 0, 0);
        int s0 = v.x, s1 = s0 + v.y, s2 = s1 + v.z, s3 = s2 + v.w;

        // wave-inclusive scan of thread totals
        int x = s3;
        #pragma unroll
        for (int off = 1; off < 64; off <<= 1) {
            int y = __shfl_up(x, off);
            if (lane >= off) x += y;
        }
        if (lane == 63) wsum[wid] = x;
        __syncthreads();
        if (wid == 0) {
            int t = (lane < 16) ? wsum[lane] : 0;
            int xx = t;
            #pragma unroll
            for (int off = 1; off < 16; off <<= 1) {
                int y = __shfl_up(xx, off);
                if (lane >= off) xx += y;
            }
            if (lane < 16) woff[lane] = xx - t;     // exclusive wave offsets
            if (lane == 15) chunk_total = xx;
        }
        __syncthreads();

        int texcl = x - s3;                          // exclusive thread offset in wave
        int offset = running + woff[wid] + texcl;
        if (i4 < N4) {
            int idx = i4 * 4;
            rp[idx]     = offset;       cur[idx]     = offset;
            rp[idx + 1] = offset + s0;  cur[idx + 1] = offset + s0;
            rp[idx + 2] = offset + s1;  cur[idx + 2] = offset + s1;
            rp[idx + 3] = offset + s2;  cur[idx + 3] = offset + s2;
        }
        running += chunk_total;
        // next-iteration barrier (after wsum writes) protects reuse of shared vars
    }
    if (tid == 0) rp[N_NODES] = running;
}

// ---------------- CSR fill (order within row arbitrary) ----------------
__global__ __launch_bounds__(256) void fill_kernel(
    const int* __restrict__ src, const int* __restrict__ dst,
    int* __restrict__ cursor, int* __restrict__ col)
{
    int i = blockIdx.x * 256 + threadIdx.x;
    if (i < E_EDGES) {
        int d = dst[i];
        int pos = atomicAdd(&cursor[d], 1);
        col[pos] = src[i];
    }
}

// ---------------- GEMM: out = A(N,128) @ W(128,128), fused epilogue ----------------
// mode 0: out = dot * ns[row]
// mode 1: out = relu( (dot + bias - mean) * rsqrt(var+eps) * gamma + beta )
// mode 2: out = dot + bias
__global__ __launch_bounds__(256) void gemm_kernel(
    const float* __restrict__ A, const float* __restrict__ W,
    float* __restrict__ out,
    const float* __restrict__ ns,
    const float* __restrict__ bias,
    const float* __restrict__ gma, const float* __restrict__ bta,
    const float* __restrict__ mean, const float* __restrict__ var,
    int mode)
{
    __shared__ float As[D][BM];    // transposed A tile: As[k][r]  (32 KB)
    __shared__ float Ws[D][D];     // Ws[k][j]                     (64 KB)

    const int t = threadIdx.x;
    const int i0 = blockIdx.x * BM;

    // stage W (fully coalesced float4 copy)
    {
        const float4* Wv = (const float4*)W;
        float4* Wsv = (float4*)&Ws[0][0];
        #pragma unroll
        for (int u = t; u < D * D / 4; u += 256) Wsv[u] = Wv[u];
    }
    // stage A transposed: lane-major over rows (LDS writes 2-way broadcast-free)
    {
        #pragma unroll
        for (int p = 0; p < (BM * D / 4) / 256; ++p) {
            int u = t + p * 256;
            int r = u & 63;
            int k4 = u >> 6;                       // 0..31
            int rr = i0 + r; if (rr >= N_NODES) rr = N_NODES - 1;
            float4 v = *(const float4*)(A + (size_t)rr * D + k4 * 4);
            As[k4 * 4 + 0][r] = v.x;
            As[k4 * 4 + 1][r] = v.y;
            As[k4 * 4 + 2][r] = v.z;
            As[k4 * 4 + 3][r] = v.w;
        }
    }
    __syncthreads();

    const int rg = t & 15;    // 16 row groups * 4 rows = 64 rows
    const int cg = t >> 4;    // 16 col groups * 8 cols = 128 cols
    float acc[4][8] = {};

    #pragma unroll 4
    for (int k = 0; k < D; ++k) {
        float4 a  = *(const float4*)&As[k][rg * 4];
        float4 b0 = *(const float4*)&Ws[k][cg * 8];
        float4 b1 = *(const float4*)&Ws[k][cg * 8 + 4];
        float av[4] = {a.x, a.y, a.z, a.w};
        float bv[8] = {b0.x, b0.y, b0.z, b0.w, b1.x, b1.y, b1.z, b1.w};
        #pragma unroll
        for (int i = 0; i < 4; ++i)
            #pragma unroll
            for (int j = 0; j < 8; ++j)
                acc[i][j] = fmaf(av[i], bv[j], acc[i][j]);
    }

    const int row0 = i0 + rg * 4;
    const int c0 = cg * 8;

    if (mode == 0) {
        #pragma unroll
        for (int i = 0; i < 4; ++i) {
            int row = row0 + i;
            if (row >= N_NODES) break;
            float s = ns[row];
            float* op = out + (size_t)row * D + c0;
            float4 o0 = {acc[i][0] * s, acc[i][1] * s, acc[i][2] * s, acc[i][3] * s};
            float4 o1 = {acc[i][4] * s, acc[i][5] * s, acc[i][6] * s, acc[i][7] * s};
            *(float4*)op = o0; *(float4*)(op + 4) = o1;
        }
    } else if (mode == 1) {
        float sc[8], sh[8];
        #pragma unroll
        for (int j = 0; j < 8; ++j) {
            float rs = rsqrtf(var[c0 + j] + BN_EPS);
            sc[j] = rs * gma[c0 + j];
            sh[j] = (bias[c0 + j] - mean[c0 + j]) * sc[j] + bta[c0 + j];
        }
        #pragma unroll
        for (int i = 0; i < 4; ++i) {
            int row = row0 + i;
            if (row >= N_NODES) break;
            float* op = out + (size_t)row * D + c0;
            float4 o0, o1;
            float* o0p = &o0.x; float* o1p = &o1.x;
            #pragma unroll
            for (int j = 0; j < 4; ++j) {
                o0p[j] = fmaxf(fmaf(acc[i][j], sc[j], sh[j]), 0.0f);
                o1p[j] = fmaxf(fmaf(acc[i][j + 4], sc[j + 4], sh[j + 4]), 0.0f);
            }
            *(float4*)op = o0; *(float4*)(op + 4) = o1;
        }
    } else {
        #pragma unroll
        for (int i = 0; i < 4; ++i) {
            int row = row0 + i;
            if (row >= N_NODES) break;
            float* op = out + (size_t)row * D + c0;
            float4 o0 = {acc[i][0] + bias[c0], acc[i][1] + bias[c0 + 1],
                         acc[i][2] + bias[c0 + 2], acc[i][3] + bias[c0 + 3]};
            float4 o1 = {acc[i][4] + bias[c0 + 4], acc[i][5] + bias[c0 + 5],
                         acc[i][6] + bias[c0 + 6], acc[i][7] + bias[c0 + 7]};
            *(float4*)op = o0; *(float4*)(op + 4) = o1;
        }
    }
}

// ---------------- SpMM: agg[n] (+)= nd[n] * sum_{e in row n} m[col[e]]  (+ sum_r brel) ----------------
// one wave per node; lane handles 2 columns (float2)
__global__ __launch_bounds__(256) void spmm_kernel(
    const float* __restrict__ m, const int* __restrict__ rowptr,
    const int* __restrict__ col, const float* __restrict__ nd,
    const float* __restrict__ brelL,   // 3*D floats or nullptr
    float* __restrict__ agg, int first)
{
    int wave = (blockIdx.x * 256 + threadIdx.x) >> 6;   // node id (grid sized exactly)
    int lane = threadIdx.x & 63;
    int n = wave;
    int beg = rowptr[n];
    int end = rowptr[n + 1];
    int j = lane * 2;

    float ax = 0.0f, ay = 0.0f;
    int e = beg;
    for (; e + 1 < end; e += 2) {
        int s0 = col[e];
        int s1 = col[e + 1];
        float2 v0 = *(const float2*)(m + (size_t)s0 * D + j);
        float2 v1 = *(const float2*)(m + (size_t)s1 * D + j);
        ax += v0.x + v1.x;
        ay += v0.y + v1.y;
    }
    if (e < end) {
        int s0 = col[e];
        float2 v0 = *(const float2*)(m + (size_t)s0 * D + j);
        ax += v0.x;
        ay += v0.y;
    }

    float scale = nd[n];
    float* ag = agg + (size_t)n * D + j;
    float rx = ax * scale, ry = ay * scale;
    if (!first) {
        float2 old = *(const float2*)ag;
        rx += old.x; ry += old.y;
    }
    if (brelL) {
        rx += brelL[j]     + brelL[D + j]     + brelL[2 * D + j];
        ry += brelL[j + 1] + brelL[D + j + 1] + brelL[2 * D + j + 1];
    }
    *(float2*)ag = make_float2(rx, ry);
}

// ---------------- launch ----------------
extern "C" void kernel_launch(void* const* d_in, const int* in_sizes, int n_in,
                              void* d_out, int out_size, void* d_ws, size_t ws_size,
                              hipStream_t stream)
{
    const float* x      = (const float*)d_in[0];
    const int* seq_src  = (const int*)d_in[1];
    const int* seq_dst  = (const int*)d_in[2];
    const int* knn_src  = (const int*)d_in[3];
    const int* knn_dst  = (const int*)d_in[4];
    const int* dis_src  = (const int*)d_in[5];
    const int* dis_dst  = (const int*)d_in[6];
    const float* Wrel   = (const float*)d_in[7];   // [3][3][128][128]
    const float* brel   = (const float*)d_in[8];   // [3][3][128]
    const float* Wfc    = (const float*)d_in[9];   // [3][128][128]
    const float* bfc    = (const float*)d_in[10];  // [3][128]
    const float* gma    = (const float*)d_in[11];  // [2][128]
    const float* bta    = (const float*)d_in[12];
    const float* rmean  = (const float*)d_in[13];
    const float* rvar   = (const float*)d_in[14];
    float* out = (float*)d_out;

    const size_t ND = (size_t)N_NODES * D;
    float* ws   = (float*)d_ws;
    float* hbuf = ws;                      // N*D
    float* mbuf = hbuf + ND;               // N*D
    float* agg  = mbuf + ND;               // N*D
    int* outdeg = (int*)(agg + ND);        // 3*N
    int* indeg  = outdeg + 3 * N_NODES;    // 3*N
    float* ns_  = (float*)(indeg + 3 * N_NODES);  // 3*N
    float* nd_  = ns_ + 3 * N_NODES;               // 3*N
    int* rowptr = (int*)(nd_ + 3 * N_NODES);       // 3*(N+1)
    int* cursor = rowptr + 3 * (N_NODES + 1);      // 3*N
    int* col    = cursor + 3 * N_NODES;            // 3*E

    const int* srcs[3] = {seq_src, knn_src, dis_src};
    const int* dsts[3] = {seq_dst, knn_dst, dis_dst};

    // ---- graph preprocessing (per call; deterministic up to fp add order) ----
    hipMemsetAsync(outdeg, 0, (size_t)6 * N_NODES * sizeof(int), stream);
    const int EB = (E_EDGES + 255) / 256;
    for (int r = 0; r < 3; ++r)
        hist_kernel<<<EB, 256, 0, stream>>>(srcs[r], dsts[r],
                                            outdeg + (size_t)r * N_NODES,
                                            indeg + (size_t)r * N_NODES);
    norm_kernel<<<dim3((N_NODES + 255) / 256, 3), 256, 0, stream>>>(outdeg, indeg, ns_, nd_);
    scan_kernel<<<3, 1024, 0, stream>>>(indeg, rowptr, cursor);
    for (int r = 0; r < 3; ++r)
        fill_kernel<<<EB, 256, 0, stream>>>(srcs[r], dsts[r],
                                            cursor + (size_t)r * N_NODES,
                                            col + (size_t)r * E_EDGES);

    // ---- layers ----
    const int GB = (N_NODES + BM - 1) / BM;         // 1563
    const int SB = N_NODES / 4;                      // 25000 blocks (4 waves each)
    const float* hcur = x;
    for (int l = 0; l < 3; ++l) {
        for (int r = 0; r < 3; ++r) {
            gemm_kernel<<<GB, 256, 0, stream>>>(
                hcur, Wrel + ((size_t)(l * 3 + r)) * D * D, mbuf,
                ns_ + (size_t)r * N_NODES,
                nullptr, nullptr, nullptr, nullptr, nullptr, 0);
            spmm_kernel<<<SB, 256, 0, stream>>>(
                mbuf, rowptr + (size_t)r * (N_NODES + 1), col + (size_t)r * E_EDGES,
                nd_ + (size_t)r * N_NODES,
                (r == 2) ? (brel + (size_t)l * 3 * D) : nullptr,
                agg, (r == 0) ? 1 : 0);
        }
        if (l < 2) {
            gemm_kernel<<<GB, 256, 0, stream>>>(
                agg, Wfc + (size_t)l * D * D, hbuf,
                nullptr, bfc + (size_t)l * D,
                gma + (size_t)l * D, bta + (size_t)l * D,
                rmean + (size_t)l * D, rvar + (size_t)l * D, 1);
            hcur = hbuf;
        } else {
            gemm_kernel<<<GB, 256, 0, stream>>>(
                agg, Wfc + (size_t)l * D * D, out,
                nullptr, bfc + (size_t)l * D,
                nullptr, nullptr, nullptr, nullptr, 2);
        }
    }
}

// Round 2
// 1458.518 us; speedup vs baseline: 1.4275x; 1.4275x over previous
//
#include <hip/hip_runtime.h>
#include <math.h>

#define N_NODES 100000
#define D 128
#define E_EDGES 600000
#define BN_EPS 1e-5f

typedef __attribute__((ext_vector_type(8))) __bf16 bf16x8;
typedef __attribute__((ext_vector_type(4))) __bf16 bf16x4;
typedef __attribute__((ext_vector_type(16))) float f32x16;

__device__ __forceinline__ int swz(int row, int c) { return c ^ ((row >> 1) & 3); }

// ---------------- degree histogram ----------------
__global__ __launch_bounds__(256) void hist_kernel(
    const int* __restrict__ src, const int* __restrict__ dst,
    int* __restrict__ outdeg, int* __restrict__ indeg)
{
    int i = blockIdx.x * 256 + threadIdx.x;
    if (i < E_EDGES) {
        atomicAdd(&outdeg[src[i]], 1);
        atomicAdd(&indeg[dst[i]], 1);
    }
}

// ---------------- norms ----------------
__global__ __launch_bounds__(256) void norm_kernel(
    const int* __restrict__ outdeg, const int* __restrict__ indeg,
    float* __restrict__ ns, float* __restrict__ nd)
{
    int n = blockIdx.x * 256 + threadIdx.x;
    int r = blockIdx.y;
    if (n < N_NODES) {
        int od = outdeg[r * N_NODES + n];
        int id = indeg[r * N_NODES + n];
        ns[r * N_NODES + n] = rsqrtf((float)(od < 1 ? 1 : od));
        nd[r * N_NODES + n] = rsqrtf((float)(id < 1 ? 1 : id));
    }
}

// ---------------- exclusive scan of in-degrees -> CSR row_ptr (+cursor copy) ----------------
__global__ __launch_bounds__(1024) void scan_kernel(
    const int* __restrict__ indeg, int* __restrict__ rowptr, int* __restrict__ cursor)
{
    const int r = blockIdx.x;
    const int4* deg4 = (const int4*)(indeg + (size_t)r * N_NODES);
    int* rp = rowptr + (size_t)r * (N_NODES + 1);
    int* cur = cursor + (size_t)r * N_NODES;

    __shared__ int wsum[16];
    __shared__ int woff[16];
    __shared__ int chunk_total;

    const int tid = threadIdx.x;
    const int lane = tid & 63;
    const int wid = tid >> 6;
    const int N4 = N_NODES / 4;

    int running = 0;
    for (int base4 = 0; base4 < N4; base4 += 1024) {
        int i4 = base4 + tid;
        int4 v = (i4 < N4) ? deg4[i4] : make_int4(0, 0, 0, 0);
        int s0 = v.x, s1 = s0 + v.y, s2 = s1 + v.z, s3 = s2 + v.w;

        int x = s3;
        #pragma unroll
        for (int off = 1; off < 64; off <<= 1) {
            int y = __shfl_up(x, off);
            if (lane >= off) x += y;
        }
        if (lane == 63) wsum[wid] = x;
        __syncthreads();
        if (wid == 0) {
            int t = (lane < 16) ? wsum[lane] : 0;
            int xx = t;
            #pragma unroll
            for (int off = 1; off < 16; off <<= 1) {
                int y = __shfl_up(xx, off);
                if (lane >= off) xx += y;
            }
            if (lane < 16) woff[lane] = xx - t;
            if (lane == 15) chunk_total = xx;
        }
        __syncthreads();

        int texcl = x - s3;
        int offset = running + woff[wid] + texcl;
        if (i4 < N4) {
            int idx = i4 * 4;
            rp[idx]     = offset;       cur[idx]     = offset;
            rp[idx + 1] = offset + s0;  cur[idx + 1] = offset + s0;
            rp[idx + 2] = offset + s1;  cur[idx + 2] = offset + s1;
            rp[idx + 3] = offset + s2;  cur[idx + 3] = offset + s2;
        }
        running += chunk_total;
    }
    if (tid == 0) rp[N_NODES] = running;
}

// ---------------- CSR fill ----------------
__global__ __launch_bounds__(256) void fill_kernel(
    const int* __restrict__ src, const int* __restrict__ dst,
    int* __restrict__ cursor, int* __restrict__ col)
{
    int i = blockIdx.x * 256 + threadIdx.x;
    if (i < E_EDGES) {
        int d = dst[i];
        int pos = atomicAdd(&cursor[d], 1);
        col[pos] = src[i];
    }
}

// ---------------- W' precompute: Wp[l,r] = Wrel[l,r] @ Wfc[l], BN-scaled, split hi/lo, stored [col][k] ----------------
__global__ __launch_bounds__(256) void wprep_kernel(
    const float* __restrict__ Wrel, const float* __restrict__ Wfc,
    const float* __restrict__ gma, const float* __restrict__ rvar,
    __bf16* __restrict__ Whi, __bf16* __restrict__ Wlo)
{
    __shared__ float W1[128][132];
    __shared__ float W2[128][132];
    const int b = blockIdx.x;   // l*3+r
    const int l = b / 3;
    const int t = threadIdx.x;

    const float* src1 = Wrel + (size_t)b * D * D;
    const float* src2 = Wfc + (size_t)l * D * D;
    #pragma unroll
    for (int p = 0; p < 16; ++p) {
        int u = t + p * 256;
        int r = u >> 5, f = u & 31;
        float4 v1 = *(const float4*)(src1 + r * D + f * 4);
        float4 v2 = *(const float4*)(src2 + r * D + f * 4);
        *(float4*)&W1[r][f * 4] = v1;
        *(float4*)&W2[r][f * 4] = v2;
    }
    __syncthreads();

    const int row = t >> 1;          // k-index of Wp
    const int cb = (t & 1) * 64;
    float acc[64];
    #pragma unroll
    for (int j = 0; j < 64; ++j) acc[j] = 0.f;
    for (int k = 0; k < 128; ++k) {
        float a = W1[row][k];
        #pragma unroll
        for (int j = 0; j < 64; ++j) acc[j] = fmaf(a, W2[k][cb + j], acc[j]);
    }
    for (int j = 0; j < 64; ++j) {
        int colj = cb + j;
        float s = 1.0f;
        if (l < 2) s = gma[l * D + colj] * rsqrtf(rvar[l * D + colj] + BN_EPS);
        float v = acc[j] * s;
        __bf16 h = (__bf16)v;
        __bf16 lo = (__bf16)(v - (float)h);
        Whi[((size_t)b * D + colj) * D + row] = h;
        Wlo[((size_t)b * D + colj) * D + row] = lo;
    }
}

// ---------------- bias precompute: bvec[l] = ((sum_r brel[l,r]) @ Wfc[l] + bfc[l]) (BN-folded) ----------------
__global__ __launch_bounds__(128) void bias_prep_kernel(
    const float* __restrict__ brel, const float* __restrict__ Wfc,
    const float* __restrict__ bfc,
    const float* __restrict__ gma, const float* __restrict__ bta,
    const float* __restrict__ rmean, const float* __restrict__ rvar,
    float* __restrict__ bvec)
{
    int j = threadIdx.x;
    int l = blockIdx.x;
    float acc = bfc[l * D + j];
    for (int k = 0; k < D; ++k) {
        float bs = brel[(l * 3 + 0) * D + k] + brel[(l * 3 + 1) * D + k] + brel[(l * 3 + 2) * D + k];
        acc = fmaf(bs, Wfc[((size_t)l * D + k) * D + j], acc);
    }
    if (l < 2) {
        float s = gma[l * D + j] * rsqrtf(rvar[l * D + j] + BN_EPS);
        acc = acc * s + (bta[l * D + j] - rmean[l * D + j] * s);
    }
    bvec[l * D + j] = acc;
}

// ---------------- SpMM: g[n] = nd[n] * sum_{e in row n} ns[col_e] * h[col_e] ----------------
__global__ __launch_bounds__(256) void spmm_kernel(
    const float* __restrict__ h, const int* __restrict__ rowptr,
    const int* __restrict__ col, const float* __restrict__ nsv,
    const float* __restrict__ ndv, float* __restrict__ g)
{
    int n = (blockIdx.x * 256 + threadIdx.x) >> 6;
    int lane = threadIdx.x & 63;
    int beg = rowptr[n], end = rowptr[n + 1];
    int j = lane * 2;
    float ax = 0.f, ay = 0.f;
    int e = beg;
    for (; e + 1 < end; e += 2) {
        int s0 = col[e], s1 = col[e + 1];
        float w0 = nsv[s0], w1 = nsv[s1];
        float2 v0 = *(const float2*)(h + (size_t)s0 * D + j);
        float2 v1 = *(const float2*)(h + (size_t)s1 * D + j);
        ax = fmaf(w0, v0.x, ax); ay = fmaf(w0, v0.y, ay);
        ax = fmaf(w1, v1.x, ax); ay = fmaf(w1, v1.y, ay);
    }
    if (e < end) {
        int s0 = col[e];
        float w0 = nsv[s0];
        float2 v0 = *(const float2*)(h + (size_t)s0 * D + j);
        ax = fmaf(w0, v0.x, ax); ay = fmaf(w0, v0.y, ay);
    }
    float sc = ndv[n];
    *(float2*)(g + (size_t)n * D + j) = make_float2(ax * sc, ay * sc);
}

// ---------------- MFMA GEMM: out (op)= A(N,128) @ Wp(128,128), bf16 hi/lo split ----------------
// mode 0: out = v ; 1: out += v ; 2: out = relu(out + v + bias) ; 3: out = out + v + bias
__global__ __launch_bounds__(256) void gemm_mfma_kernel(
    const float* __restrict__ A,
    const __bf16* __restrict__ Whi, const __bf16* __restrict__ Wlo,  // [col][k]
    float* __restrict__ out, const float* __restrict__ bias, int mode)
{
    __shared__ __bf16 Ah[128 * 32], Al[128 * 32], Bh[128 * 32], Bl[128 * 32]; // 32 KB

    const int t = threadIdx.x;
    const int lane = t & 63;
    const int wid = t >> 6;
    const int row0 = blockIdx.x * 128;

    f32x16 acc[4];
    #pragma unroll
    for (int nt = 0; nt < 4; ++nt)
        #pragma unroll
        for (int i = 0; i < 16; ++i) acc[nt][i] = 0.0f;

    const int arow = lane & 31;
    const int kgrp = lane >> 5;

    for (int ks = 0; ks < 4; ++ks) {
        // stage A tile: 128 rows x 32 k (fp32 -> bf16 hi/lo, swizzled 16B chunks)
        #pragma unroll
        for (int p = 0; p < 4; ++p) {
            int u = t + p * 256;
            int r = u >> 3;
            int q = u & 7;
            int gr = row0 + r; if (gr > N_NODES - 1) gr = N_NODES - 1;
            float4 v = *(const float4*)(A + (size_t)gr * D + ks * 32 + q * 4);
            bf16x4 hv, lv;
            hv[0] = (__bf16)v.x; hv[1] = (__bf16)v.y; hv[2] = (__bf16)v.z; hv[3] = (__bf16)v.w;
            lv[0] = (__bf16)(v.x - (float)hv[0]); lv[1] = (__bf16)(v.y - (float)hv[1]);
            lv[2] = (__bf16)(v.z - (float)hv[2]); lv[3] = (__bf16)(v.w - (float)hv[3]);
            int idx = r * 32 + swz(r, q >> 1) * 8 + (q & 1) * 4;
            *(bf16x4*)&Ah[idx] = hv;
            *(bf16x4*)&Al[idx] = lv;
        }
        // stage W k-slice: 128 cols x 32 k (bf16, swizzled)
        {
            int colj = t >> 1;
            int kh = (t & 1) * 2;
            const __bf16* sh = Whi + (size_t)colj * D + ks * 32 + kh * 8;
            const __bf16* sl = Wlo + (size_t)colj * D + ks * 32 + kh * 8;
            #pragma unroll
            for (int cc = 0; cc < 2; ++cc) {
                int c = kh + cc;
                int idx = colj * 32 + swz(colj, c) * 8;
                *(bf16x8*)&Bh[idx] = *(const bf16x8*)(sh + cc * 8);
                *(bf16x8*)&Bl[idx] = *(const bf16x8*)(sl + cc * 8);
            }
        }
        __syncthreads();
        #pragma unroll
        for (int ksub = 0; ksub < 2; ++ksub) {
            int ac = ksub * 2 + kgrp;
            int arow_g = wid * 32 + arow;
            int aidx = arow_g * 32 + swz(arow_g, ac) * 8;
            bf16x8 ah = *(const bf16x8*)&Ah[aidx];
            bf16x8 al = *(const bf16x8*)&Al[aidx];
            #pragma unroll
            for (int nt = 0; nt < 4; ++nt) {
                int colg = nt * 32 + arow;
                int bidx = colg * 32 + swz(colg, ac) * 8;
                bf16x8 bh = *(const bf16x8*)&Bh[bidx];
                bf16x8 bl = *(const bf16x8*)&Bl[bidx];
                acc[nt] = __builtin_amdgcn_mfma_f32_32x32x16_bf16(ah, bh, acc[nt], 0, 0, 0);
                acc[nt] = __builtin_amdgcn_mfma_f32_32x32x16_bf16(ah, bl, acc[nt], 0, 0, 0);
                acc[nt] = __builtin_amdgcn_mfma_f32_32x32x16_bf16(al, bh, acc[nt], 0, 0, 0);
            }
        }
        __syncthreads();
    }

    // epilogue: D layout col=lane&31, row=(reg&3)+8*(reg>>2)+4*(lane>>5)
    const int colb = lane & 31;
    const int rq = lane >> 5;
    #pragma unroll
    for (int nt = 0; nt < 4; ++nt) {
        int colg = nt * 32 + colb;
        float bv = (mode >= 2) ? bias[colg] : 0.0f;
        #pragma unroll
        for (int reg = 0; reg < 16; ++reg) {
            int rowl = wid * 32 + (reg & 3) + 8 * (reg >> 2) + 4 * rq;
            int grow = row0 + rowl;
            if (grow < N_NODES) {
                float* p = out + (size_t)grow * D + colg;
                float v = acc[nt][reg];
                if (mode == 0) { *p = v; }
                else if (mode == 1) { *p = *p + v; }
                else if (mode == 2) { float z = *p + v + bv; *p = z > 0.f ? z : 0.f; }
                else { *p = *p + v + bv; }
            }
        }
    }
}

// ---------------- launch ----------------
extern "C" void kernel_launch(void* const* d_in, const int* in_sizes, int n_in,
                              void* d_out, int out_size, void* d_ws, size_t ws_size,
                              hipStream_t stream)
{
    const float* x      = (const float*)d_in[0];
    const int* seq_src  = (const int*)d_in[1];
    const int* seq_dst  = (const int*)d_in[2];
    const int* knn_src  = (const int*)d_in[3];
    const int* knn_dst  = (const int*)d_in[4];
    const int* dis_src  = (const int*)d_in[5];
    const int* dis_dst  = (const int*)d_in[6];
    const float* Wrel   = (const float*)d_in[7];   // [3][3][128][128]
    const float* brel   = (const float*)d_in[8];   // [3][3][128]
    const float* Wfc    = (const float*)d_in[9];   // [3][128][128]
    const float* bfc    = (const float*)d_in[10];  // [3][128]
    const float* gma    = (const float*)d_in[11];  // [2][128]
    const float* bta    = (const float*)d_in[12];
    const float* rmean  = (const float*)d_in[13];
    const float* rvar   = (const float*)d_in[14];
    float* out = (float*)d_out;

    const size_t ND = (size_t)N_NODES * D;
    float* ws   = (float*)d_ws;
    float* h0   = ws;                         // N*D
    float* h1   = h0 + ND;                    // N*D
    float* g    = h1 + ND;                    // N*D
    float* ns_  = g + ND;                     // 3*N
    float* nd_  = ns_ + 3 * N_NODES;          // 3*N
    float* bvec = nd_ + 3 * N_NODES;          // 3*128
    __bf16* Whi = (__bf16*)(bvec + 3 * D);    // 9*128*128
    __bf16* Wlo = Whi + (size_t)9 * D * D;
    int* outdeg = (int*)(Wlo + (size_t)9 * D * D);   // 3*N
    int* indeg  = outdeg + 3 * N_NODES;               // 3*N
    int* rowptr = indeg + 3 * N_NODES;                // 3*(N+1)
    int* cursor = rowptr + 3 * (N_NODES + 1);         // 3*N
    int* col    = cursor + 3 * N_NODES;               // 3*E

    const int* srcs[3] = {seq_src, knn_src, dis_src};
    const int* dsts[3] = {seq_dst, knn_dst, dis_dst};

    // ---- graph preprocessing ----
    hipMemsetAsync(outdeg, 0, (size_t)6 * N_NODES * sizeof(int), stream);
    const int EB = (E_EDGES + 255) / 256;
    for (int r = 0; r < 3; ++r)
        hist_kernel<<<EB, 256, 0, stream>>>(srcs[r], dsts[r],
                                            outdeg + (size_t)r * N_NODES,
                                            indeg + (size_t)r * N_NODES);
    norm_kernel<<<dim3((N_NODES + 255) / 256, 3), 256, 0, stream>>>(outdeg, indeg, ns_, nd_);
    scan_kernel<<<3, 1024, 0, stream>>>(indeg, rowptr, cursor);
    for (int r = 0; r < 3; ++r)
        fill_kernel<<<EB, 256, 0, stream>>>(srcs[r], dsts[r],
                                            cursor + (size_t)r * N_NODES,
                                            col + (size_t)r * E_EDGES);

    // ---- weight/bias precompute ----
    wprep_kernel<<<9, 256, 0, stream>>>(Wrel, Wfc, gma, rvar, Whi, Wlo);
    bias_prep_kernel<<<3, 128, 0, stream>>>(brel, Wfc, bfc, gma, bta, rmean, rvar, bvec);

    // ---- layers ----
    const int SB = N_NODES / 4;                 // 25000 blocks (4 waves each)
    const int GB = (N_NODES + 127) / 128;       // 782
    for (int l = 0; l < 3; ++l) {
        const float* hc = (l == 0) ? x : ((l == 1) ? h0 : h1);
        float* hn = (l == 0) ? h0 : ((l == 1) ? h1 : out);
        for (int r = 0; r < 3; ++r) {
            spmm_kernel<<<SB, 256, 0, stream>>>(
                hc, rowptr + (size_t)r * (N_NODES + 1), col + (size_t)r * E_EDGES,
                ns_ + (size_t)r * N_NODES, nd_ + (size_t)r * N_NODES, g);
            int mode;
            if (r < 2) mode = (r == 0) ? 0 : 1;
            else       mode = (l < 2) ? 2 : 3;
            gemm_mfma_kernel<<<GB, 256, 0, stream>>>(
                g, Whi + (size_t)(l * 3 + r) * D * D, Wlo + (size_t)(l * 3 + r) * D * D,
                hn, bvec + (size_t)l * D, mode);
        }
    }
}

// Round 3
// 1030.893 us; speedup vs baseline: 2.0196x; 1.4148x over previous
//
#include <hip/hip_runtime.h>
#include <math.h>

#define N_NODES 100000
#define D 128
#define E_EDGES 600000
#define BN_EPS 1e-5f

typedef __attribute__((ext_vector_type(8))) __bf16 bf16x8;
typedef __attribute__((ext_vector_type(4))) __bf16 bf16x4;
typedef __attribute__((ext_vector_type(16))) float f32x16;

// swizzle for 128-k A tile: chunk q in [0,16), 8-row stripes
__device__ __forceinline__ int qswz(int row, int q) {
    return (q & 8) | ((q ^ row) & 7);
}
// swizzle for 32-k B tile (4 chunks of 8 bf16)
__device__ __forceinline__ int swz(int row, int c) { return c ^ ((row >> 1) & 3); }

// ---------------- degree histogram ----------------
__global__ __launch_bounds__(256) void hist_kernel(
    const int* __restrict__ src, const int* __restrict__ dst,
    int* __restrict__ outdeg, int* __restrict__ indeg)
{
    int i = blockIdx.x * 256 + threadIdx.x;
    if (i < E_EDGES) {
        atomicAdd(&outdeg[src[i]], 1);
        atomicAdd(&indeg[dst[i]], 1);
    }
}

// ---------------- norms ----------------
__global__ __launch_bounds__(256) void norm_kernel(
    const int* __restrict__ outdeg, const int* __restrict__ indeg,
    float* __restrict__ ns, float* __restrict__ nd)
{
    int n = blockIdx.x * 256 + threadIdx.x;
    int r = blockIdx.y;
    if (n < N_NODES) {
        int od = outdeg[r * N_NODES + n];
        int id = indeg[r * N_NODES + n];
        ns[r * N_NODES + n] = rsqrtf((float)(od < 1 ? 1 : od));
        nd[r * N_NODES + n] = rsqrtf((float)(id < 1 ? 1 : id));
    }
}

// ---------------- exclusive scan of in-degrees -> CSR row_ptr (+cursor copy) ----------------
__global__ __launch_bounds__(1024) void scan_kernel(
    const int* __restrict__ indeg, int* __restrict__ rowptr, int* __restrict__ cursor)
{
    const int r = blockIdx.x;
    const int4* deg4 = (const int4*)(indeg + (size_t)r * N_NODES);
    int* rp = rowptr + (size_t)r * (N_NODES + 1);
    int* cur = cursor + (size_t)r * N_NODES;

    __shared__ int wsum[16];
    __shared__ int woff[16];
    __shared__ int chunk_total;

    const int tid = threadIdx.x;
    const int lane = tid & 63;
    const int wid = tid >> 6;
    const int N4 = N_NODES / 4;

    int running = 0;
    for (int base4 = 0; base4 < N4; base4 += 1024) {
        int i4 = base4 + tid;
        int4 v = (i4 < N4) ? deg4[i4] : make_int4(0, 0, 0, 0);
        int s0 = v.x, s1 = s0 + v.y, s2 = s1 + v.z, s3 = s2 + v.w;

        int x = s3;
        #pragma unroll
        for (int off = 1; off < 64; off <<= 1) {
            int y = __shfl_up(x, off);
            if (lane >= off) x += y;
        }
        if (lane == 63) wsum[wid] = x;
        __syncthreads();
        if (wid == 0) {
            int t = (lane < 16) ? wsum[lane] : 0;
            int xx = t;
            #pragma unroll
            for (int off = 1; off < 16; off <<= 1) {
                int y = __shfl_up(xx, off);
                if (lane >= off) xx += y;
            }
            if (lane < 16) woff[lane] = xx - t;
            if (lane == 15) chunk_total = xx;
        }
        __syncthreads();

        int texcl = x - s3;
        int offset = running + woff[wid] + texcl;
        if (i4 < N4) {
            int idx = i4 * 4;
            rp[idx]     = offset;       cur[idx]     = offset;
            rp[idx + 1] = offset + s0;  cur[idx + 1] = offset + s0;
            rp[idx + 2] = offset + s1;  cur[idx + 2] = offset + s1;
            rp[idx + 3] = offset + s2;  cur[idx + 3] = offset + s2;
        }
        running += chunk_total;
    }
    if (tid == 0) rp[N_NODES] = running;
}

// ---------------- CSR fill ----------------
__global__ __launch_bounds__(256) void fill_kernel(
    const int* __restrict__ src, const int* __restrict__ dst,
    int* __restrict__ cursor, int* __restrict__ col)
{
    int i = blockIdx.x * 256 + threadIdx.x;
    if (i < E_EDGES) {
        int d = dst[i];
        int pos = atomicAdd(&cursor[d], 1);
        col[pos] = src[i];
    }
}

// ---------------- W' precompute: Wp[l,r] = Wrel[l,r] @ Wfc[l], BN-scaled, split hi/lo, stored [col][k] ----------------
__global__ __launch_bounds__(256) void wprep_kernel(
    const float* __restrict__ Wrel, const float* __restrict__ Wfc,
    const float* __restrict__ gma, const float* __restrict__ rvar,
    __bf16* __restrict__ Whi, __bf16* __restrict__ Wlo)
{
    __shared__ float W1[128][132];
    __shared__ float W2[128][132];
    const int b = blockIdx.x;   // l*3+r
    const int l = b / 3;
    const int t = threadIdx.x;

    const float* src1 = Wrel + (size_t)b * D * D;
    const float* src2 = Wfc + (size_t)l * D * D;
    #pragma unroll
    for (int p = 0; p < 16; ++p) {
        int u = t + p * 256;
        int r = u >> 5, f = u & 31;
        float4 v1 = *(const float4*)(src1 + r * D + f * 4);
        float4 v2 = *(const float4*)(src2 + r * D + f * 4);
        *(float4*)&W1[r][f * 4] = v1;
        *(float4*)&W2[r][f * 4] = v2;
    }
    __syncthreads();

    const int row = t >> 1;          // k-index of Wp
    const int cb = (t & 1) * 64;
    float acc[64];
    #pragma unroll
    for (int j = 0; j < 64; ++j) acc[j] = 0.f;
    for (int k = 0; k < 128; ++k) {
        float a = W1[row][k];
        #pragma unroll
        for (int j = 0; j < 64; ++j) acc[j] = fmaf(a, W2[k][cb + j], acc[j]);
    }
    for (int j = 0; j < 64; ++j) {
        int colj = cb + j;
        float s = 1.0f;
        if (l < 2) s = gma[l * D + colj] * rsqrtf(rvar[l * D + colj] + BN_EPS);
        float v = acc[j] * s;
        __bf16 h = (__bf16)v;
        __bf16 lo = (__bf16)(v - (float)h);
        Whi[((size_t)b * D + colj) * D + row] = h;
        Wlo[((size_t)b * D + colj) * D + row] = lo;
    }
}

// ---------------- bias precompute: bvec[l] = ((sum_r brel[l,r]) @ Wfc[l] + bfc[l]) (BN-folded) ----------------
__global__ __launch_bounds__(128) void bias_prep_kernel(
    const float* __restrict__ brel, const float* __restrict__ Wfc,
    const float* __restrict__ bfc,
    const float* __restrict__ gma, const float* __restrict__ bta,
    const float* __restrict__ rmean, const float* __restrict__ rvar,
    float* __restrict__ bvec)
{
    int j = threadIdx.x;
    int l = blockIdx.x;
    float acc = bfc[l * D + j];
    for (int k = 0; k < D; ++k) {
        float bs = brel[(l * 3 + 0) * D + k] + brel[(l * 3 + 1) * D + k] + brel[(l * 3 + 2) * D + k];
        acc = fmaf(bs, Wfc[((size_t)l * D + k) * D + j], acc);
    }
    if (l < 2) {
        float s = gma[l * D + j] * rsqrtf(rvar[l * D + j] + BN_EPS);
        acc = acc * s + (bta[l * D + j] - rmean[l * D + j] * s);
    }
    bvec[l * D + j] = acc;
}

// ---------------- fused layer: gather(SpMM) -> bf16 hi/lo LDS -> MFMA vs W' (3 relations) -> epilogue ----------------
__global__ __launch_bounds__(256) void fused_layer_kernel(
    const float* __restrict__ h,
    const int* __restrict__ rowptr,   // [3][N+1]
    const int* __restrict__ col,      // [3][E]
    const float* __restrict__ nsv,    // [3][N]
    const float* __restrict__ ndv,    // [3][N]
    const __bf16* __restrict__ Whi,   // [3][col][k], this layer
    const __bf16* __restrict__ Wlo,
    float* __restrict__ out, const float* __restrict__ bias, int relu)
{
    __shared__ __bf16 Ah[128 * 128];   // 32 KB
    __shared__ __bf16 Al[128 * 128];   // 32 KB
    __shared__ __bf16 Bh[128 * 32];    // 8 KB
    __shared__ __bf16 Bl[128 * 32];    // 8 KB

    const int t = threadIdx.x;
    const int lane = t & 63;
    const int wid = t >> 6;
    const int row0 = blockIdx.x * 128;

    const int grp = lane >> 3;    // 8 groups per wave
    const int gl = lane & 7;      // lane within group

    f32x16 acc[4];
    #pragma unroll
    for (int nt = 0; nt < 4; ++nt)
        #pragma unroll
        for (int i = 0; i < 16; ++i) acc[nt][i] = 0.0f;

    for (int r = 0; r < 3; ++r) {
        const int* rp = rowptr + (size_t)r * (N_NODES + 1);
        const int* cl = col + (size_t)r * E_EDGES;
        const float* ns_ = nsv + (size_t)r * N_NODES;
        const float* nd_ = ndv + (size_t)r * N_NODES;

        // ---- gather phase: each 8-lane group accumulates 4 rows in registers ----
        #pragma unroll
        for (int rr = 0; rr < 4; ++rr) {
            int rowl = wid * 32 + grp * 4 + rr;
            int grow = row0 + rowl;
            float4 a0 = {0,0,0,0}, a1 = {0,0,0,0}, a2 = {0,0,0,0}, a3 = {0,0,0,0};
            if (grow < N_NODES) {
                int beg = rp[grow], end = rp[grow + 1];
                for (int e = beg; e < end; ++e) {
                    int s = cl[e];
                    float w = ns_[s];
                    const float* hp = h + (size_t)s * D + gl * 4;
                    float4 v0 = *(const float4*)(hp);
                    float4 v1 = *(const float4*)(hp + 32);
                    float4 v2 = *(const float4*)(hp + 64);
                    float4 v3 = *(const float4*)(hp + 96);
                    a0.x = fmaf(w, v0.x, a0.x); a0.y = fmaf(w, v0.y, a0.y);
                    a0.z = fmaf(w, v0.z, a0.z); a0.w = fmaf(w, v0.w, a0.w);
                    a1.x = fmaf(w, v1.x, a1.x); a1.y = fmaf(w, v1.y, a1.y);
                    a1.z = fmaf(w, v1.z, a1.z); a1.w = fmaf(w, v1.w, a1.w);
                    a2.x = fmaf(w, v2.x, a2.x); a2.y = fmaf(w, v2.y, a2.y);
                    a2.z = fmaf(w, v2.z, a2.z); a2.w = fmaf(w, v2.w, a2.w);
                    a3.x = fmaf(w, v3.x, a3.x); a3.y = fmaf(w, v3.y, a3.y);
                    a3.z = fmaf(w, v3.z, a3.z); a3.w = fmaf(w, v3.w, a3.w);
                }
                float sc = nd_[grow];
                a0.x *= sc; a0.y *= sc; a0.z *= sc; a0.w *= sc;
                a1.x *= sc; a1.y *= sc; a1.z *= sc; a1.w *= sc;
                a2.x *= sc; a2.y *= sc; a2.z *= sc; a2.w *= sc;
                a3.x *= sc; a3.y *= sc; a3.z *= sc; a3.w *= sc;
            }
            float4 av[4] = {a0, a1, a2, a3};
            #pragma unroll
            for (int j = 0; j < 4; ++j) {
                // k-cols gl*4 + 32*j .. +3  -> chunk q = (gl>>1) + 4*j, sub (gl&1)*4
                int q = (gl >> 1) + 4 * j;
                int idx = rowl * 128 + qswz(rowl, q) * 8 + (gl & 1) * 4;
                bf16x4 hv, lv;
                float* ap = &av[j].x;
                #pragma unroll
                for (int c = 0; c < 4; ++c) {
                    __bf16 hb = (__bf16)ap[c];
                    hv[c] = hb;
                    lv[c] = (__bf16)(ap[c] - (float)hb);
                }
                *(bf16x4*)&Ah[idx] = hv;
                *(bf16x4*)&Al[idx] = lv;
            }
        }

        // ---- MFMA phase over 4 K-slices ----
        for (int ks = 0; ks < 4; ++ks) {
            // stage B slice: 128 cols x 32 k (hi/lo)
            {
                int colj = t >> 1;
                int kh = (t & 1) * 2;
                const __bf16* sh = Whi + (size_t)r * D * D + (size_t)colj * D + ks * 32 + kh * 8;
                const __bf16* sl = Wlo + (size_t)r * D * D + (size_t)colj * D + ks * 32 + kh * 8;
                #pragma unroll
                for (int cc = 0; cc < 2; ++cc) {
                    int c = kh + cc;
                    int idx = colj * 32 + swz(colj, c) * 8;
                    *(bf16x8*)&Bh[idx] = *(const bf16x8*)(sh + cc * 8);
                    *(bf16x8*)&Bl[idx] = *(const bf16x8*)(sl + cc * 8);
                }
            }
            __syncthreads();   // A-writes (ks==0) and B-writes visible

            const int arow = lane & 31;
            const int kgrp = lane >> 5;
            #pragma unroll
            for (int ksub = 0; ksub < 2; ++ksub) {
                int ac = ksub * 2 + kgrp;
                int arow_g = wid * 32 + arow;
                int q = ks * 4 + ac;
                int aidx = arow_g * 128 + qswz(arow_g, q) * 8;
                bf16x8 ahv = *(const bf16x8*)&Ah[aidx];
                bf16x8 alv = *(const bf16x8*)&Al[aidx];
                #pragma unroll
                for (int nt = 0; nt < 4; ++nt) {
                    int colg = nt * 32 + arow;
                    int bidx = colg * 32 + swz(colg, ac) * 8;
                    bf16x8 bhv = *(const bf16x8*)&Bh[bidx];
                    bf16x8 blv = *(const bf16x8*)&Bl[bidx];
                    acc[nt] = __builtin_amdgcn_mfma_f32_32x32x16_bf16(ahv, bhv, acc[nt], 0, 0, 0);
                    acc[nt] = __builtin_amdgcn_mfma_f32_32x32x16_bf16(ahv, blv, acc[nt], 0, 0, 0);
                    acc[nt] = __builtin_amdgcn_mfma_f32_32x32x16_bf16(alv, bhv, acc[nt], 0, 0, 0);
                }
            }
            __syncthreads();   // protect B (and A on relation change) before re-stage
        }
    }

    // ---- epilogue: bias (+ ReLU), single write ----
    const int colb = lane & 31;
    const int rq = lane >> 5;
    #pragma unroll
    for (int nt = 0; nt < 4; ++nt) {
        int colg = nt * 32 + colb;
        float bv = bias[colg];
        #pragma unroll
        for (int reg = 0; reg < 16; ++reg) {
            int rowl = wid * 32 + (reg & 3) + 8 * (reg >> 2) + 4 * rq;
            int grow = row0 + rowl;
            if (grow < N_NODES) {
                float z = acc[nt][reg] + bv;
                if (relu) z = z > 0.f ? z : 0.f;
                out[(size_t)grow * D + colg] = z;
            }
        }
    }
}

// ---------------- launch ----------------
extern "C" void kernel_launch(void* const* d_in, const int* in_sizes, int n_in,
                              void* d_out, int out_size, void* d_ws, size_t ws_size,
                              hipStream_t stream)
{
    const float* x      = (const float*)d_in[0];
    const int* seq_src  = (const int*)d_in[1];
    const int* seq_dst  = (const int*)d_in[2];
    const int* knn_src  = (const int*)d_in[3];
    const int* knn_dst  = (const int*)d_in[4];
    const int* dis_src  = (const int*)d_in[5];
    const int* dis_dst  = (const int*)d_in[6];
    const float* Wrel   = (const float*)d_in[7];   // [3][3][128][128]
    const float* brel   = (const float*)d_in[8];   // [3][3][128]
    const float* Wfc    = (const float*)d_in[9];   // [3][128][128]
    const float* bfc    = (const float*)d_in[10];  // [3][128]
    const float* gma    = (const float*)d_in[11];  // [2][128]
    const float* bta    = (const float*)d_in[12];
    const float* rmean  = (const float*)d_in[13];
    const float* rvar   = (const float*)d_in[14];
    float* out = (float*)d_out;

    const size_t ND = (size_t)N_NODES * D;
    float* ws   = (float*)d_ws;
    float* h0   = ws;                         // N*D
    float* h1   = h0 + ND;                    // N*D
    float* ns_  = h1 + ND;                    // 3*N
    float* nd_  = ns_ + 3 * N_NODES;          // 3*N
    float* bvec = nd_ + 3 * N_NODES;          // 3*128
    __bf16* Whi = (__bf16*)(bvec + 3 * D);    // 9*128*128
    __bf16* Wlo = Whi + (size_t)9 * D * D;
    int* outdeg = (int*)(Wlo + (size_t)9 * D * D);   // 3*N
    int* indeg  = outdeg + 3 * N_NODES;               // 3*N
    int* rowptr = indeg + 3 * N_NODES;                // 3*(N+1)
    int* cursor = rowptr + 3 * (N_NODES + 1);         // 3*N
    int* col    = cursor + 3 * N_NODES;               // 3*E

    const int* srcs[3] = {seq_src, knn_src, dis_src};
    const int* dsts[3] = {seq_dst, knn_dst, dis_dst};

    // ---- graph preprocessing ----
    hipMemsetAsync(outdeg, 0, (size_t)6 * N_NODES * sizeof(int), stream);
    const int EB = (E_EDGES + 255) / 256;
    for (int r = 0; r < 3; ++r)
        hist_kernel<<<EB, 256, 0, stream>>>(srcs[r], dsts[r],
                                            outdeg + (size_t)r * N_NODES,
                                            indeg + (size_t)r * N_NODES);
    norm_kernel<<<dim3((N_NODES + 255) / 256, 3), 256, 0, stream>>>(outdeg, indeg, ns_, nd_);
    scan_kernel<<<3, 1024, 0, stream>>>(indeg, rowptr, cursor);
    for (int r = 0; r < 3; ++r)
        fill_kernel<<<EB, 256, 0, stream>>>(srcs[r], dsts[r],
                                            cursor + (size_t)r * N_NODES,
                                            col + (size_t)r * E_EDGES);

    // ---- weight/bias precompute ----
    wprep_kernel<<<9, 256, 0, stream>>>(Wrel, Wfc, gma, rvar, Whi, Wlo);
    bias_prep_kernel<<<3, 128, 0, stream>>>(brel, Wfc, bfc, gma, bta, rmean, rvar, bvec);

    // ---- layers (fully fused) ----
    const int GB = (N_NODES + 127) / 128;   // 782
    fused_layer_kernel<<<GB, 256, 0, stream>>>(
        x, rowptr, col, ns_, nd_, Whi, Wlo, h0, bvec, 1);
    fused_layer_kernel<<<GB, 256, 0, stream>>>(
        h0, rowptr, col, ns_, nd_, Whi + (size_t)3 * D * D, Wlo + (size_t)3 * D * D,
        h1, bvec + D, 1);
    fused_layer_kernel<<<GB, 256, 0, stream>>>(
        h1, rowptr, col, ns_, nd_, Whi + (size_t)6 * D * D, Wlo + (size_t)6 * D * D,
        out, bvec + 2 * D, 0);
}

// Round 4
// 902.509 us; speedup vs baseline: 2.3069x; 1.1423x over previous
//
#include <hip/hip_runtime.h>
#include <math.h>

#define N_NODES 100000
#define D 128
#define E_EDGES 600000
#define BN_EPS 1e-5f

typedef __attribute__((ext_vector_type(8))) __bf16 bf16x8;
typedef __attribute__((ext_vector_type(4))) __bf16 bf16x4;
typedef __attribute__((ext_vector_type(16))) float f32x16;

// swizzle for 128-k A tile: chunk q in [0,16), 8-row stripes
__device__ __forceinline__ int qswz(int row, int q) {
    return (q & 8) | ((q ^ row) & 7);
}
// swizzle for 32-k B tile (4 chunks of 8 bf16)
__device__ __forceinline__ int swz(int row, int c) { return c ^ ((row >> 1) & 3); }

// ---------------- degree histogram (all 3 relations, 4 edges/thread) ----------------
__global__ __launch_bounds__(256) void hist_kernel(
    const int* __restrict__ s0, const int* __restrict__ d0,
    const int* __restrict__ s1, const int* __restrict__ d1,
    const int* __restrict__ s2, const int* __restrict__ d2,
    int* __restrict__ outdeg, int* __restrict__ indeg)
{
    const int r = blockIdx.y;
    const int* src = (r == 0) ? s0 : ((r == 1) ? s1 : s2);
    const int* dst = (r == 0) ? d0 : ((r == 1) ? d1 : d2);
    int* od = outdeg + (size_t)r * N_NODES;
    int* id = indeg + (size_t)r * N_NODES;
    int i4 = blockIdx.x * 256 + threadIdx.x;
    if (i4 < E_EDGES / 4) {
        int4 s = ((const int4*)src)[i4];
        int4 d = ((const int4*)dst)[i4];
        atomicAdd(&od[s.x], 1); atomicAdd(&od[s.y], 1);
        atomicAdd(&od[s.z], 1); atomicAdd(&od[s.w], 1);
        atomicAdd(&id[d.x], 1); atomicAdd(&id[d.y], 1);
        atomicAdd(&id[d.z], 1); atomicAdd(&id[d.w], 1);
    }
}

// ---------------- norms ----------------
__global__ __launch_bounds__(256) void norm_kernel(
    const int* __restrict__ outdeg, const int* __restrict__ indeg,
    float* __restrict__ ns, float* __restrict__ nd)
{
    int n = blockIdx.x * 256 + threadIdx.x;
    int r = blockIdx.y;
    if (n < N_NODES) {
        int od = outdeg[r * N_NODES + n];
        int id = indeg[r * N_NODES + n];
        ns[r * N_NODES + n] = rsqrtf((float)(od < 1 ? 1 : od));
        nd[r * N_NODES + n] = rsqrtf((float)(id < 1 ? 1 : id));
    }
}

// ---------------- exclusive scan of in-degrees -> CSR row_ptr (+cursor copy) ----------------
__global__ __launch_bounds__(1024) void scan_kernel(
    const int* __restrict__ indeg, int* __restrict__ rowptr, int* __restrict__ cursor)
{
    const int r = blockIdx.x;
    const int4* deg4 = (const int4*)(indeg + (size_t)r * N_NODES);
    int* rp = rowptr + (size_t)r * (N_NODES + 1);
    int* cur = cursor + (size_t)r * N_NODES;

    __shared__ int wsum[16];
    __shared__ int woff[16];
    __shared__ int chunk_total;

    const int tid = threadIdx.x;
    const int lane = tid & 63;
    const int wid = tid >> 6;
    const int N4 = N_NODES / 4;

    int running = 0;
    for (int base4 = 0; base4 < N4; base4 += 1024) {
        int i4 = base4 + tid;
        int4 v = (i4 < N4) ? deg4[i4] : make_int4(0, 0, 0, 0);
        int s0 = v.x, s1 = s0 + v.y, s2 = s1 + v.z, s3 = s2 + v.w;

        int x = s3;
        #pragma unroll
        for (int off = 1; off < 64; off <<= 1) {
            int y = __shfl_up(x, off);
            if (lane >= off) x += y;
        }
        if (lane == 63) wsum[wid] = x;
        __syncthreads();
        if (wid == 0) {
            int t = (lane < 16) ? wsum[lane] : 0;
            int xx = t;
            #pragma unroll
            for (int off = 1; off < 16; off <<= 1) {
                int y = __shfl_up(xx, off);
                if (lane >= off) xx += y;
            }
            if (lane < 16) woff[lane] = xx - t;
            if (lane == 15) chunk_total = xx;
        }
        __syncthreads();

        int texcl = x - s3;
        int offset = running + woff[wid] + texcl;
        if (i4 < N4) {
            int idx = i4 * 4;
            rp[idx]     = offset;       cur[idx]     = offset;
            rp[idx + 1] = offset + s0;  cur[idx + 1] = offset + s0;
            rp[idx + 2] = offset + s1;  cur[idx + 2] = offset + s1;
            rp[idx + 3] = offset + s2;  cur[idx + 3] = offset + s2;
        }
        running += chunk_total;
    }
    if (tid == 0) rp[N_NODES] = running;
}

// ---------------- CSR fill: edge record {src, ns[src]} (all 3 relations) ----------------
__global__ __launch_bounds__(256) void fill_kernel(
    const int* __restrict__ s0, const int* __restrict__ d0,
    const int* __restrict__ s1, const int* __restrict__ d1,
    const int* __restrict__ s2, const int* __restrict__ d2,
    const float* __restrict__ nsv,
    int* __restrict__ cursor, int2* __restrict__ eint)
{
    const int r = blockIdx.y;
    const int* src = (r == 0) ? s0 : ((r == 1) ? s1 : s2);
    const int* dst = (r == 0) ? d0 : ((r == 1) ? d1 : d2);
    int* cur = cursor + (size_t)r * N_NODES;
    int2* eg = eint + (size_t)r * E_EDGES;
    const float* ns_ = nsv + (size_t)r * N_NODES;
    int i = blockIdx.x * 256 + threadIdx.x;
    if (i < E_EDGES) {
        int s = src[i];
        int d = dst[i];
        int pos = atomicAdd(&cur[d], 1);
        eg[pos] = make_int2(s, __float_as_int(ns_[s]));
    }
}

// ---------------- W' precompute: Wp[l,r] = Wrel[l,r] @ Wfc[l], BN-scaled, split hi/lo, stored [col][k] ----------------
__global__ __launch_bounds__(256) void wprep_kernel(
    const float* __restrict__ Wrel, const float* __restrict__ Wfc,
    const float* __restrict__ gma, const float* __restrict__ rvar,
    __bf16* __restrict__ Whi, __bf16* __restrict__ Wlo)
{
    __shared__ float W1[128][132];
    __shared__ float W2[128][132];
    const int b = blockIdx.x;   // l*3+r
    const int l = b / 3;
    const int t = threadIdx.x;

    const float* src1 = Wrel + (size_t)b * D * D;
    const float* src2 = Wfc + (size_t)l * D * D;
    #pragma unroll
    for (int p = 0; p < 16; ++p) {
        int u = t + p * 256;
        int r = u >> 5, f = u & 31;
        float4 v1 = *(const float4*)(src1 + r * D + f * 4);
        float4 v2 = *(const float4*)(src2 + r * D + f * 4);
        *(float4*)&W1[r][f * 4] = v1;
        *(float4*)&W2[r][f * 4] = v2;
    }
    __syncthreads();

    const int row = t >> 1;          // k-index of Wp
    const int cb = (t & 1) * 64;
    float4 acc4[16];
    #pragma unroll
    for (int j = 0; j < 16; ++j) acc4[j] = make_float4(0.f, 0.f, 0.f, 0.f);
    for (int k = 0; k < 128; ++k) {
        float a = W1[row][k];
        #pragma unroll
        for (int j = 0; j < 16; ++j) {
            float4 w = *(const float4*)&W2[k][cb + j * 4];
            acc4[j].x = fmaf(a, w.x, acc4[j].x);
            acc4[j].y = fmaf(a, w.y, acc4[j].y);
            acc4[j].z = fmaf(a, w.z, acc4[j].z);
            acc4[j].w = fmaf(a, w.w, acc4[j].w);
        }
    }
    for (int j = 0; j < 64; ++j) {
        int colj = cb + j;
        float s = 1.0f;
        if (l < 2) s = gma[l * D + colj] * rsqrtf(rvar[l * D + colj] + BN_EPS);
        float v = (&acc4[j >> 2].x)[j & 3] * s;
        __bf16 h = (__bf16)v;
        __bf16 lo = (__bf16)(v - (float)h);
        Whi[((size_t)b * D + colj) * D + row] = h;
        Wlo[((size_t)b * D + colj) * D + row] = lo;
    }
}

// ---------------- bias precompute ----------------
__global__ __launch_bounds__(128) void bias_prep_kernel(
    const float* __restrict__ brel, const float* __restrict__ Wfc,
    const float* __restrict__ bfc,
    const float* __restrict__ gma, const float* __restrict__ bta,
    const float* __restrict__ rmean, const float* __restrict__ rvar,
    float* __restrict__ bvec)
{
    int j = threadIdx.x;
    int l = blockIdx.x;
    float acc = bfc[l * D + j];
    for (int k = 0; k < D; ++k) {
        float bs = brel[(l * 3 + 0) * D + k] + brel[(l * 3 + 1) * D + k] + brel[(l * 3 + 2) * D + k];
        acc = fmaf(bs, Wfc[((size_t)l * D + k) * D + j], acc);
    }
    if (l < 2) {
        float s = gma[l * D + j] * rsqrtf(rvar[l * D + j] + BN_EPS);
        acc = acc * s + (bta[l * D + j] - rmean[l * D + j] * s);
    }
    bvec[l * D + j] = acc;
}

// ---------------- fused layer: gather(SpMM) -> bf16 hi/lo LDS -> MFMA vs W' (3 relations) ----------------
// 512 threads = 8 waves; wave w: rows (w&3)*32..+31, cols (w>>2)*64..+63
__global__ __launch_bounds__(512, 4) void fused_layer_kernel(
    const float* __restrict__ h,
    const int* __restrict__ rowptr,   // [3][N+1]
    const int2* __restrict__ eint,    // [3][E] {src, ns[src]}
    const float* __restrict__ ndv,    // [3][N]
    const __bf16* __restrict__ Whi,   // [3][col][k], this layer
    const __bf16* __restrict__ Wlo,
    float* __restrict__ out, const float* __restrict__ bias, int relu)
{
    __shared__ __bf16 Ah[128 * 128];   // 32 KB
    __shared__ __bf16 Al[128 * 128];   // 32 KB
    __shared__ __bf16 Bh[128 * 32];    // 8 KB
    __shared__ __bf16 Bl[128 * 32];    // 8 KB

    const int t = threadIdx.x;
    const int lane = t & 63;
    const int wid = t >> 6;           // 0..7
    const int wrow = wid & 3;         // 32-row block
    const int wcol = wid >> 2;        // 64-col half
    const int row0 = blockIdx.x * 128;

    const int g = t >> 3;             // 64 gather groups
    const int gl = t & 7;             // lane within group

    f32x16 acc[2];
    #pragma unroll
    for (int nt = 0; nt < 2; ++nt)
        #pragma unroll
        for (int i = 0; i < 16; ++i) acc[nt][i] = 0.0f;

    for (int r = 0; r < 3; ++r) {
        const int* rp = rowptr + (size_t)r * (N_NODES + 1);
        const int2* eg = eint + (size_t)r * E_EDGES;
        const float* nd_ = ndv + (size_t)r * N_NODES;

        // ---- gather phase: each 8-lane group accumulates 2 rows ----
        #pragma unroll
        for (int rr = 0; rr < 2; ++rr) {
            int rowl = g * 2 + rr;
            int grow = row0 + rowl;
            float4 a0 = {0,0,0,0}, a1 = {0,0,0,0}, a2 = {0,0,0,0}, a3 = {0,0,0,0};
            if (grow < N_NODES) {
                int beg = rp[grow], end = rp[grow + 1];
                float sc = nd_[grow];
                int e = beg;
                for (; e + 1 < end; e += 2) {
                    int2 e0 = eg[e];
                    int2 e1 = eg[e + 1];
                    float w0 = __int_as_float(e0.y);
                    float w1 = __int_as_float(e1.y);
                    const float* hp0 = h + (size_t)e0.x * D + gl * 4;
                    const float* hp1 = h + (size_t)e1.x * D + gl * 4;
                    float4 u0 = *(const float4*)(hp0);
                    float4 u1 = *(const float4*)(hp0 + 32);
                    float4 u2 = *(const float4*)(hp0 + 64);
                    float4 u3 = *(const float4*)(hp0 + 96);
                    float4 v0 = *(const float4*)(hp1);
                    float4 v1 = *(const float4*)(hp1 + 32);
                    float4 v2 = *(const float4*)(hp1 + 64);
                    float4 v3 = *(const float4*)(hp1 + 96);
                    a0.x = fmaf(w0, u0.x, a0.x); a0.y = fmaf(w0, u0.y, a0.y);
                    a0.z = fmaf(w0, u0.z, a0.z); a0.w = fmaf(w0, u0.w, a0.w);
                    a1.x = fmaf(w0, u1.x, a1.x); a1.y = fmaf(w0, u1.y, a1.y);
                    a1.z = fmaf(w0, u1.z, a1.z); a1.w = fmaf(w0, u1.w, a1.w);
                    a2.x = fmaf(w0, u2.x, a2.x); a2.y = fmaf(w0, u2.y, a2.y);
                    a2.z = fmaf(w0, u2.z, a2.z); a2.w = fmaf(w0, u2.w, a2.w);
                    a3.x = fmaf(w0, u3.x, a3.x); a3.y = fmaf(w0, u3.y, a3.y);
                    a3.z = fmaf(w0, u3.z, a3.z); a3.w = fmaf(w0, u3.w, a3.w);
                    a0.x = fmaf(w1, v0.x, a0.x); a0.y = fmaf(w1, v0.y, a0.y);
                    a0.z = fmaf(w1, v0.z, a0.z); a0.w = fmaf(w1, v0.w, a0.w);
                    a1.x = fmaf(w1, v1.x, a1.x); a1.y = fmaf(w1, v1.y, a1.y);
                    a1.z = fmaf(w1, v1.z, a1.z); a1.w = fmaf(w1, v1.w, a1.w);
                    a2.x = fmaf(w1, v2.x, a2.x); a2.y = fmaf(w1, v2.y, a2.y);
                    a2.z = fmaf(w1, v2.z, a2.z); a2.w = fmaf(w1, v2.w, a2.w);
                    a3.x = fmaf(w1, v3.x, a3.x); a3.y = fmaf(w1, v3.y, a3.y);
                    a3.z = fmaf(w1, v3.z, a3.z); a3.w = fmaf(w1, v3.w, a3.w);
                }
                if (e < end) {
                    int2 e0 = eg[e];
                    float w0 = __int_as_float(e0.y);
                    const float* hp0 = h + (size_t)e0.x * D + gl * 4;
                    float4 u0 = *(const float4*)(hp0);
                    float4 u1 = *(const float4*)(hp0 + 32);
                    float4 u2 = *(const float4*)(hp0 + 64);
                    float4 u3 = *(const float4*)(hp0 + 96);
                    a0.x = fmaf(w0, u0.x, a0.x); a0.y = fmaf(w0, u0.y, a0.y);
                    a0.z = fmaf(w0, u0.z, a0.z); a0.w = fmaf(w0, u0.w, a0.w);
                    a1.x = fmaf(w0, u1.x, a1.x); a1.y = fmaf(w0, u1.y, a1.y);
                    a1.z = fmaf(w0, u1.z, a1.z); a1.w = fmaf(w0, u1.w, a1.w);
                    a2.x = fmaf(w0, u2.x, a2.x); a2.y = fmaf(w0, u2.y, a2.y);
                    a2.z = fmaf(w0, u2.z, a2.z); a2.w = fmaf(w0, u2.w, a2.w);
                    a3.x = fmaf(w0, u3.x, a3.x); a3.y = fmaf(w0, u3.y, a3.y);
                    a3.z = fmaf(w0, u3.z, a3.z); a3.w = fmaf(w0, u3.w, a3.w);
                }
                a0.x *= sc; a0.y *= sc; a0.z *= sc; a0.w *= sc;
                a1.x *= sc; a1.y *= sc; a1.z *= sc; a1.w *= sc;
                a2.x *= sc; a2.y *= sc; a2.z *= sc; a2.w *= sc;
                a3.x *= sc; a3.y *= sc; a3.z *= sc; a3.w *= sc;
            }
            float4 av[4] = {a0, a1, a2, a3};
            #pragma unroll
            for (int j = 0; j < 4; ++j) {
                int q = (gl >> 1) + 4 * j;
                int idx = rowl * 128 + qswz(rowl, q) * 8 + (gl & 1) * 4;
                bf16x4 hv, lv;
                float* ap = &av[j].x;
                #pragma unroll
                for (int c = 0; c < 4; ++c) {
                    __bf16 hb = (__bf16)ap[c];
                    hv[c] = hb;
                    lv[c] = (__bf16)(ap[c] - (float)hb);
                }
                *(bf16x4*)&Ah[idx] = hv;
                *(bf16x4*)&Al[idx] = lv;
            }
        }

        // ---- MFMA phase over 4 K-slices ----
        for (int ks = 0; ks < 4; ++ks) {
            // stage B slice: 128 cols x 32 k (hi/lo); 512 threads, 1 chunk each
            {
                int colj = t >> 2;
                int c = t & 3;
                int idx = colj * 32 + swz(colj, c) * 8;
                const __bf16* sh = Whi + (size_t)r * D * D + (size_t)colj * D + ks * 32 + c * 8;
                const __bf16* sl = Wlo + (size_t)r * D * D + (size_t)colj * D + ks * 32 + c * 8;
                *(bf16x8*)&Bh[idx] = *(const bf16x8*)sh;
                *(bf16x8*)&Bl[idx] = *(const bf16x8*)sl;
            }
            __syncthreads();   // A-writes (ks==0) and B-writes visible

            const int arow = lane & 31;
            const int kgrp = lane >> 5;
            #pragma unroll
            for (int ksub = 0; ksub < 2; ++ksub) {
                int ac = ksub * 2 + kgrp;
                int arow_g = wrow * 32 + arow;
                int q = ks * 4 + ac;
                int aidx = arow_g * 128 + qswz(arow_g, q) * 8;
                bf16x8 ahv = *(const bf16x8*)&Ah[aidx];
                bf16x8 alv = *(const bf16x8*)&Al[aidx];
                #pragma unroll
                for (int nt = 0; nt < 2; ++nt) {
                    int colg = wcol * 64 + nt * 32 + arow;
                    int bidx = colg * 32 + swz(colg, ac) * 8;
                    bf16x8 bhv = *(const bf16x8*)&Bh[bidx];
                    bf16x8 blv = *(const bf16x8*)&Bl[bidx];
                    acc[nt] = __builtin_amdgcn_mfma_f32_32x32x16_bf16(ahv, bhv, acc[nt], 0, 0, 0);
                    acc[nt] = __builtin_amdgcn_mfma_f32_32x32x16_bf16(ahv, blv, acc[nt], 0, 0, 0);
                    acc[nt] = __builtin_amdgcn_mfma_f32_32x32x16_bf16(alv, bhv, acc[nt], 0, 0, 0);
                }
            }
            __syncthreads();   // protect B (and A on relation change) before re-stage
        }
    }

    // ---- epilogue: bias (+ ReLU), single write ----
    const int colb = lane & 31;
    const int rq = lane >> 5;
    #pragma unroll
    for (int nt = 0; nt < 2; ++nt) {
        int colg = wcol * 64 + nt * 32 + colb;
        float bv = bias[colg];
        #pragma unroll
        for (int reg = 0; reg < 16; ++reg) {
            int rowl = wrow * 32 + (reg & 3) + 8 * (reg >> 2) + 4 * rq;
            int grow = row0 + rowl;
            if (grow < N_NODES) {
                float z = acc[nt][reg] + bv;
                if (relu) z = z > 0.f ? z : 0.f;
                out[(size_t)grow * D + colg] = z;
            }
        }
    }
}

// ---------------- launch ----------------
extern "C" void kernel_launch(void* const* d_in, const int* in_sizes, int n_in,
                              void* d_out, int out_size, void* d_ws, size_t ws_size,
                              hipStream_t stream)
{
    const float* x      = (const float*)d_in[0];
    const int* seq_src  = (const int*)d_in[1];
    const int* seq_dst  = (const int*)d_in[2];
    const int* knn_src  = (const int*)d_in[3];
    const int* knn_dst  = (const int*)d_in[4];
    const int* dis_src  = (const int*)d_in[5];
    const int* dis_dst  = (const int*)d_in[6];
    const float* Wrel   = (const float*)d_in[7];   // [3][3][128][128]
    const float* brel   = (const float*)d_in[8];   // [3][3][128]
    const float* Wfc    = (const float*)d_in[9];   // [3][128][128]
    const float* bfc    = (const float*)d_in[10];  // [3][128]
    const float* gma    = (const float*)d_in[11];  // [2][128]
    const float* bta    = (const float*)d_in[12];
    const float* rmean  = (const float*)d_in[13];
    const float* rvar   = (const float*)d_in[14];
    float* out = (float*)d_out;

    const size_t ND = (size_t)N_NODES * D;
    float* ws   = (float*)d_ws;
    float* h0   = ws;                         // N*D
    float* h1   = h0 + ND;                    // N*D
    float* ns_  = h1 + ND;                    // 3*N
    float* nd_  = ns_ + 3 * N_NODES;          // 3*N
    float* bvec = nd_ + 3 * N_NODES;          // 3*128
    __bf16* Whi = (__bf16*)(bvec + 3 * D);    // 9*128*128
    __bf16* Wlo = Whi + (size_t)9 * D * D;
    int* outdeg = (int*)(Wlo + (size_t)9 * D * D);   // 3*N
    int* indeg  = outdeg + 3 * N_NODES;               // 3*N
    int* rowptr = indeg + 3 * N_NODES;                // 3*(N+1) (+1 pad for alignment)
    int* cursor = rowptr + 3 * (N_NODES + 1) + 1;     // 3*N
    int2* eint  = (int2*)(cursor + 3 * N_NODES);      // 3*E {src, w}

    // ---- graph preprocessing ----
    hipMemsetAsync(outdeg, 0, (size_t)6 * N_NODES * sizeof(int), stream);
    hist_kernel<<<dim3((E_EDGES / 4 + 255) / 256, 3), 256, 0, stream>>>(
        seq_src, seq_dst, knn_src, knn_dst, dis_src, dis_dst, outdeg, indeg);
    norm_kernel<<<dim3((N_NODES + 255) / 256, 3), 256, 0, stream>>>(outdeg, indeg, ns_, nd_);
    scan_kernel<<<3, 1024, 0, stream>>>(indeg, rowptr, cursor);
    fill_kernel<<<dim3((E_EDGES + 255) / 256, 3), 256, 0, stream>>>(
        seq_src, seq_dst, knn_src, knn_dst, dis_src, dis_dst, ns_, cursor, eint);

    // ---- weight/bias precompute ----
    wprep_kernel<<<9, 256, 0, stream>>>(Wrel, Wfc, gma, rvar, Whi, Wlo);
    bias_prep_kernel<<<3, 128, 0, stream>>>(brel, Wfc, bfc, gma, bta, rmean, rvar, bvec);

    // ---- layers (fully fused) ----
    const int GB = (N_NODES + 127) / 128;   // 782
    fused_layer_kernel<<<GB, 512, 0, stream>>>(
        x, rowptr, eint, nd_, Whi, Wlo, h0, bvec, 1);
    fused_layer_kernel<<<GB, 512, 0, stream>>>(
        h0, rowptr, eint, nd_, Whi + (size_t)3 * D * D, Wlo + (size_t)3 * D * D,
        h1, bvec + D, 1);
    fused_layer_kernel<<<GB, 512, 0, stream>>>(
        h1, rowptr, eint, nd_, Whi + (size_t)6 * D * D, Wlo + (size_t)6 * D * D,
        out, bvec + 2 * D, 0);
}